// Round 1
// baseline (589.824 us; speedup 1.0000x reference)
//
#include <hip/hip_runtime.h>
#include <math.h>

#define Dd 192
#define Hh 192
#define Ww 192
#define K  11
#define R  5

struct G11 { float g[K]; };

// ---------------- Pass 1: conv along W; builds 5 fields from gr/gt ----------
__global__ __launch_bounds__(192) void k1_convW(const float* __restrict__ gr,
                                                const float* __restrict__ gt,
                                                float* __restrict__ bufA,
                                                int dStart, int Lin, G11 gw) {
    const int w  = threadIdx.x;        // 0..191
    const int h  = blockIdx.x;         // 0..191
    const int ld = blockIdx.y;         // 0..Lin-1
    const int d  = dStart + ld;

    __shared__ float xs[Ww];
    __shared__ float ys[Ww];

    const size_t idx = ((size_t)d * Hh + h) * Ww + w;
    const float x = (gr[idx] + 1.0f) * 0.5f;
    const float y = (gt[idx] + 1.0f) * 0.5f;
    xs[w] = x; ys[w] = y;
    __syncthreads();

    float s1 = 0.f, s2 = 0.f, s3 = 0.f, s4 = 0.f, s5 = 0.f;
#pragma unroll
    for (int t = 0; t < K; ++t) {
        const int ww = w + t - R;
        const bool ok = (ww >= 0) && (ww < Ww);
        const float xv = ok ? xs[ww] : 0.0f;
        const float yv = ok ? ys[ww] : 0.0f;
        const float g = gw.g[t];
        s1 += g * xv;
        s2 += g * yv;
        s3 += g * (xv * xv);
        s4 += g * (yv * yv);
        s5 += g * (xv * yv);
    }

    const size_t fs = (size_t)Lin * Hh * Ww;
    const size_t o  = ((size_t)ld * Hh + h) * Ww + w;
    bufA[o]          = s1;
    bufA[o + fs]     = s2;
    bufA[o + 2 * fs] = s3;
    bufA[o + 3 * fs] = s4;
    bufA[o + 4 * fs] = s5;
}

// ---------------- Pass 2: conv along H ----------------
__global__ __launch_bounds__(256) void k2_convH(const float* __restrict__ bufA,
                                                float* __restrict__ bufB,
                                                int Lin, G11 gw) {
    const size_t total = (size_t)Lin * Hh * Ww;
    const size_t i = (size_t)blockIdx.x * 256 + threadIdx.x;
    if (i >= total) return;

    const int w  = (int)(i % Ww);
    const int h  = (int)((i / Ww) % Hh);
    const int ld = (int)(i / ((size_t)Ww * Hh));

    const size_t fs = total;
    float a0 = 0.f, a1 = 0.f, a2 = 0.f, a3 = 0.f, a4 = 0.f;
#pragma unroll
    for (int t = 0; t < K; ++t) {
        const int hh = h + t - R;
        if (hh < 0 || hh >= Hh) continue;
        const size_t src = ((size_t)ld * Hh + hh) * Ww + w;
        const float g = gw.g[t];
        a0 += g * bufA[src];
        a1 += g * bufA[src + fs];
        a2 += g * bufA[src + 2 * fs];
        a3 += g * bufA[src + 3 * fs];
        a4 += g * bufA[src + 4 * fs];
    }
    bufB[i]          = a0;
    bufB[i + fs]     = a1;
    bufB[i + 2 * fs] = a2;
    bufB[i + 3 * fs] = a3;
    bufB[i + 4 * fs] = a4;
}

// ---------------- Pass 3: conv along D + SSIM map + reduction ----------------
__global__ __launch_bounds__(256) void k3_convD_ssim(const float* __restrict__ bufB,
                                                     int dStart, int Lin,
                                                     int dOut0, int dOut1,
                                                     G11 gw,
                                                     double* __restrict__ acc) {
    const size_t nOut = (size_t)(dOut1 - dOut0) * Hh * Ww;
    const size_t i = (size_t)blockIdx.x * 256 + threadIdx.x;

    float val = 0.0f;
    if (i < nOut) {
        const int w = (int)(i % Ww);
        const int h = (int)((i / Ww) % Hh);
        const int d = dOut0 + (int)(i / ((size_t)Ww * Hh));

        const size_t fs = (size_t)Lin * Hh * Ww;
        float m1 = 0.f, m2 = 0.f, e11 = 0.f, e22 = 0.f, e12 = 0.f;
#pragma unroll
        for (int t = 0; t < K; ++t) {
            const int dd = d + t - R;
            if (dd < 0 || dd >= Dd) continue;
            const int ld = dd - dStart;
            const size_t src = ((size_t)ld * Hh + h) * Ww + w;
            const float g = gw.g[t];
            m1  += g * bufB[src];
            m2  += g * bufB[src + fs];
            e11 += g * bufB[src + 2 * fs];
            e22 += g * bufB[src + 3 * fs];
            e12 += g * bufB[src + 4 * fs];
        }
        const float mu1sq = m1 * m1;
        const float mu2sq = m2 * m2;
        const float mu12  = m1 * m2;
        const float s11 = e11 - mu1sq;
        const float s22 = e22 - mu2sq;
        const float s12 = e12 - mu12;
        const float C1 = 1e-4f, C2 = 9e-4f;
        const float num = (2.0f * mu12 + C1) * (2.0f * s12 + C2);
        const float den = (mu1sq + mu2sq + C1) * (s11 + s22 + C2);
        val = num / den;
    }

    // block reduction: wave shuffle + LDS across 4 waves
    float v = val;
#pragma unroll
    for (int o = 32; o > 0; o >>= 1) v += __shfl_down(v, o);
    __shared__ float wsum[4];
    const int lane = threadIdx.x & 63;
    const int wid  = threadIdx.x >> 6;
    if (lane == 0) wsum[wid] = v;
    __syncthreads();
    if (threadIdx.x == 0) {
        const float s = wsum[0] + wsum[1] + wsum[2] + wsum[3];
        atomicAdd(acc, (double)s);
    }
}

// ---------------- Final: scalar ----------------
__global__ void k4_final(const double* __restrict__ acc, float* __restrict__ out) {
    if (threadIdx.x == 0) {
        const double n = (double)((size_t)Dd * Hh * Ww);
        out[0] = (float)(1.0 - (*acc) / n);
    }
}

extern "C" void kernel_launch(void* const* d_in, const int* in_sizes, int n_in,
                              void* d_out, int out_size, void* d_ws, size_t ws_size,
                              hipStream_t stream) {
    const float* gr = (const float*)d_in[0];
    const float* gt = (const float*)d_in[1];
    float* out = (float*)d_out;

    // 1D normalized gaussian weights (outer-product factorization of the
    // reference 3D window; normalization factorizes exactly).
    G11 gw;
    {
        double e[K], s = 0.0;
        for (int i = 0; i < K; ++i) {
            const double a = (double)((i - R) * (i - R));
            e[i] = exp(-a / (2.0 * 1.5 * 1.5));
            s += e[i];
        }
        for (int i = 0; i < K; ++i) gw.g[i] = (float)(e[i] / s);
    }

    double* acc = (double*)d_ws;
    hipMemsetAsync(d_ws, 0, sizeof(double), stream);

    // Workspace partition: [acc (256B)] [bufA: 5*Lmax planes] [bufB: 5*Lmax planes]
    const size_t plane = (size_t)Hh * Ww;                  // elements per plane
    const size_t perRowBytes = 10 * plane * sizeof(float); // 2 bufs x 5 fields
    size_t avail = (ws_size > 256) ? (ws_size - 256) : 0;
    int Lcap = (int)(avail / perRowBytes);
    int T = Lcap - 2 * R;
    if (T > Dd) T = Dd;
    if (T < 1)  T = 1;          // requires ~16 MB workspace minimum
    int Lmax = T + 2 * R;
    if (Lmax > Dd) Lmax = Dd;

    float* bufA = (float*)((char*)d_ws + 256);
    float* bufB = bufA + 5 * (size_t)Lmax * plane;

    for (int d0 = 0; d0 < Dd; d0 += T) {
        const int d1     = (d0 + T < Dd) ? (d0 + T) : Dd;
        const int dStart = (d0 - R > 0) ? (d0 - R) : 0;
        const int dEnd   = (d1 + R < Dd) ? (d1 + R) : Dd;
        const int Lin    = dEnd - dStart;

        dim3 g1(Hh, Lin);
        k1_convW<<<g1, 192, 0, stream>>>(gr, gt, bufA, dStart, Lin, gw);

        const size_t tot = (size_t)Lin * plane;
        k2_convH<<<(unsigned)((tot + 255) / 256), 256, 0, stream>>>(bufA, bufB, Lin, gw);

        const size_t nOut = (size_t)(d1 - d0) * plane;
        k3_convD_ssim<<<(unsigned)((nOut + 255) / 256), 256, 0, stream>>>(
            bufB, dStart, Lin, d0, d1, gw, acc);
    }

    k4_final<<<1, 64, 0, stream>>>(acc, out);
}

// Round 2
// 217.624 us; speedup vs baseline: 2.7103x; 2.7103x over previous
//
#include <hip/hip_runtime.h>
#include <math.h>

#define Dd 192
#define Hh 192
#define Ww 192
#define K  11
#define R  5

#define WT 64
#define HT 8
#define DC 16
#define NTHREADS 512
#define HALO_W (WT + 2*R)   // 74
#define HALO_H (HT + 2*R)   // 18
#define XS_P   76           // padded LDS stride for halo rows

struct G11 { float g[K]; };

// One fused kernel: separable 11^3 gaussian blur of 5 fields (x, y, x^2, y^2, xy)
// + SSIM map + global mean, sliding along D with a register ring buffer.
__global__ __launch_bounds__(NTHREADS, 4) void fused_ssim(
    const float* __restrict__ gr, const float* __restrict__ gt,
    G11 gw, double* __restrict__ acc)
{
    __shared__ float xs[HALO_H][XS_P];
    __shared__ float ys[HALO_H][XS_P];
    __shared__ float cw[5][HALO_H][WT];   // conv-W results for 5 fields
    __shared__ float wsum[NTHREADS / 64];

    const int tid = threadIdx.x;
    const int tw  = tid & (WT - 1);       // 0..63
    const int th  = tid >> 6;             // 0..7
    const int w0  = blockIdx.x * WT;
    const int h0  = blockIdx.y * HT;
    const int d0  = blockIdx.z * DC;

    // conv-D ring buffer: last 11 planes of the 5 2D-blurred fields
    float hist[K][5];
#pragma unroll
    for (int t = 0; t < K; ++t)
#pragma unroll
        for (int f = 0; f < 5; ++f) hist[t][f] = 0.0f;

    float ssim_acc = 0.0f;

    for (int iz = 0; iz < DC + 2 * R; ++iz) {   // 26 input planes
        const int z = d0 - R + iz;
        const bool zok = (z >= 0) && (z < Dd);

        // ---- stage x,y halo plane (74 x 18) into LDS ----
#pragma unroll
        for (int k = 0; k < 3; ++k) {
            const int p = tid + k * NTHREADS;
            if (p < HALO_W * HALO_H) {
                const int hr = p / HALO_W;
                const int wc = p - hr * HALO_W;
                const int gww = w0 - R + wc;
                const int gh  = h0 - R + hr;
                float xv = 0.0f, yv = 0.0f;
                if (zok && gww >= 0 && gww < Ww && gh >= 0 && gh < Hh) {
                    const size_t idx = ((size_t)z * Hh + gh) * Ww + gww;
                    xv = (gr[idx] + 1.0f) * 0.5f;
                    yv = (gt[idx] + 1.0f) * 0.5f;
                }
                xs[hr][wc] = xv;
                ys[hr][wc] = yv;
            }
        }
        __syncthreads();

        // ---- conv along W at 64 x 18 positions (includes h-halo rows) ----
#pragma unroll
        for (int k = 0; k < 3; ++k) {
            const int p = tid + k * NTHREADS;
            if (p < WT * HALO_H) {
                const int hr = p >> 6;
                const int wc = p & 63;
                float s0 = 0.f, s1 = 0.f, s2 = 0.f, s3 = 0.f, s4 = 0.f;
#pragma unroll
                for (int t = 0; t < K; ++t) {
                    const float xv = xs[hr][wc + t];
                    const float yv = ys[hr][wc + t];
                    const float g  = gw.g[t];
                    s0 += g * xv;
                    s1 += g * yv;
                    s2 += g * (xv * xv);
                    s3 += g * (yv * yv);
                    s4 += g * (xv * yv);
                }
                cw[0][hr][wc] = s0;
                cw[1][hr][wc] = s1;
                cw[2][hr][wc] = s2;
                cw[3][hr][wc] = s3;
                cw[4][hr][wc] = s4;
            }
        }
        __syncthreads();

        // ---- conv along H at this thread's (tw, th) ----
        float b0 = 0.f, b1 = 0.f, b2 = 0.f, b3 = 0.f, b4 = 0.f;
#pragma unroll
        for (int t = 0; t < K; ++t) {
            const float g = gw.g[t];
            b0 += g * cw[0][th + t][tw];
            b1 += g * cw[1][th + t][tw];
            b2 += g * cw[2][th + t][tw];
            b3 += g * cw[3][th + t][tw];
            b4 += g * cw[4][th + t][tw];
        }

        // ---- shift ring, append ----
#pragma unroll
        for (int t = 0; t < K - 1; ++t)
#pragma unroll
            for (int f = 0; f < 5; ++f) hist[t][f] = hist[t + 1][f];
        hist[K - 1][0] = b0; hist[K - 1][1] = b1; hist[K - 1][2] = b2;
        hist[K - 1][3] = b3; hist[K - 1][4] = b4;

        // ---- conv along D complete for output plane od = z - R ----
        if (iz >= 2 * R) {
            float m1 = 0.f, m2 = 0.f, e11 = 0.f, e22 = 0.f, e12 = 0.f;
#pragma unroll
            for (int t = 0; t < K; ++t) {
                const float g = gw.g[t];
                m1  += g * hist[t][0];
                m2  += g * hist[t][1];
                e11 += g * hist[t][2];
                e22 += g * hist[t][3];
                e12 += g * hist[t][4];
            }
            const float mu1sq = m1 * m1;
            const float mu2sq = m2 * m2;
            const float mu12  = m1 * m2;
            const float s11 = e11 - mu1sq;
            const float s22 = e22 - mu2sq;
            const float s12 = e12 - mu12;
            const float C1 = 1e-4f, C2 = 9e-4f;
            const float num = (2.0f * mu12 + C1) * (2.0f * s12 + C2);
            const float den = (mu1sq + mu2sq + C1) * (s11 + s22 + C2);
            ssim_acc += num / den;
        }
    }

    // ---- block reduction: wave shuffle + LDS + one atomic per block ----
    float v = ssim_acc;
#pragma unroll
    for (int o = 32; o > 0; o >>= 1) v += __shfl_down(v, o);
    const int lane = tid & 63;
    const int wid  = tid >> 6;
    if (lane == 0) wsum[wid] = v;
    __syncthreads();
    if (tid == 0) {
        float s = 0.f;
#pragma unroll
        for (int i = 0; i < NTHREADS / 64; ++i) s += wsum[i];
        atomicAdd(acc, (double)s);
    }
}

__global__ void k4_final(const double* __restrict__ acc, float* __restrict__ out) {
    if (threadIdx.x == 0) {
        const double n = (double)((size_t)Dd * Hh * Ww);
        out[0] = (float)(1.0 - (*acc) / n);
    }
}

extern "C" void kernel_launch(void* const* d_in, const int* in_sizes, int n_in,
                              void* d_out, int out_size, void* d_ws, size_t ws_size,
                              hipStream_t stream) {
    const float* gr = (const float*)d_in[0];
    const float* gt = (const float*)d_in[1];
    float* out = (float*)d_out;

    // 1D normalized gaussian weights (exact outer-product factorization of
    // the reference 3D window).
    G11 gw;
    {
        double e[K], s = 0.0;
        for (int i = 0; i < K; ++i) {
            const double a = (double)((i - R) * (i - R));
            e[i] = exp(-a / (2.0 * 1.5 * 1.5));
            s += e[i];
        }
        for (int i = 0; i < K; ++i) gw.g[i] = (float)(e[i] / s);
    }

    double* acc = (double*)d_ws;
    hipMemsetAsync(d_ws, 0, sizeof(double), stream);

    dim3 grid(Ww / WT, Hh / HT, Dd / DC);   // 3 x 24 x 12 = 864 blocks
    fused_ssim<<<grid, NTHREADS, 0, stream>>>(gr, gt, gw, acc);

    k4_final<<<1, 64, 0, stream>>>(acc, out);
}

// Round 4
// 121.045 us; speedup vs baseline: 4.8728x; 1.7979x over previous
//
#include <hip/hip_runtime.h>
#include <hip/hip_fp16.h>
#include <math.h>
#include <string.h>

#define Dd 192
#define Hh 192
#define Ww 192
#define K  11
#define R  5

#define TW 32            // tile width (output cols)
#define TH 16            // tile height (output rows)
#define DC 12            // output planes per chunk (22 input planes = 2*11)
#define NT 256           // threads per block
#define NG (TW/2)        // 16 half2 groups across W
#define HH_ (TH + 2*R)   // 26 halo rows
#define SP 24            // staged dword stride per row (21 pairs + pad)

struct GW { unsigned int g2[K]; };   // half2(g,g) bit patterns

static __device__ __forceinline__ __half2 u2h2(unsigned int u) {
    union { unsigned int u; __half2 h; } x; x.u = u; return x.h;
}
static __device__ __forceinline__ unsigned int h22u(__half2 h) {
    union { __half2 h; unsigned int u; } x; x.h = h; return x.u;
}
static __device__ __forceinline__ unsigned int pk(float a, float b) {
    typedef __fp16 f16x2 __attribute__((ext_vector_type(2)));
    f16x2 r = __builtin_amdgcn_cvt_pkrtz(a, b);
    union { f16x2 v; unsigned int u; } x; x.v = r; return x.u;
}

__global__ __launch_bounds__(NT, 4) void fused_ssim(
    const float* __restrict__ gr, const float* __restrict__ gt,
    GW gw, double* __restrict__ acc)
{
    // staged fields (fp16 pairs): 0:x 1:y 2:x^2 3:y^2 4:xy
    __shared__ unsigned int stg[5][HH_][SP];     // 12.5 KB
    __shared__ unsigned int cwl[5][HH_][NG];     // 8.3 KB (conv-W results)
    __shared__ float wsum[NT / 64];

    const int tid = threadIdx.x;
    const int wg  = tid & (NG - 1);   // half2 group 0..15
    const int th  = tid >> 4;         // output row 0..15
    const int w0  = blockIdx.x * TW;
    const int h0  = blockIdx.y * TH;
    const int d0  = blockIdx.z * DC;

    __half2 hist[K][5];               // ring: 11 planes x 5 fields (2 cols packed)
    float ssim_acc = 0.0f;

    for (int c = 0; c < 2; ++c) {
#pragma unroll
        for (int j = 0; j < K; ++j) {
            const int iz = c * K + j;
            const int z  = d0 - R + iz;
            const bool zok = (z >= 0) && (z < Dd);

            // ---------------- stage: load + rescale + products + fp16 pack ----
            for (int k = 0; k < 3; ++k) {
                const int q = tid + k * NT;
                if (q < HH_ * SP) {
                    const int r  = q / SP;
                    const int pc = q - r * SP;
                    const int gh = h0 - R + r;
                    const int gx = w0 - R + 2 * pc;
                    float x0 = 0.f, x1 = 0.f, y0 = 0.f, y1 = 0.f;
                    if (zok && gh >= 0 && gh < Hh) {
                        const int base = (z * Hh + gh) * Ww;
                        if (gx >= 0 && gx < Ww)         { x0 = (gr[base+gx]  +1.f)*.5f; y0 = (gt[base+gx]  +1.f)*.5f; }
                        if (gx+1 >= 0 && gx+1 < Ww)     { x1 = (gr[base+gx+1]+1.f)*.5f; y1 = (gt[base+gx+1]+1.f)*.5f; }
                    }
                    stg[0][r][pc] = pk(x0, x1);
                    stg[1][r][pc] = pk(y0, y1);
                    stg[2][r][pc] = pk(x0*x0, x1*x1);
                    stg[3][r][pc] = pk(y0*y0, y1*y1);
                    stg[4][r][pc] = pk(x0*y0, x1*y1);
                }
            }
            __syncthreads();

            // ---------------- conv-W (pk_fma, alignbit for odd taps) ----------
            for (int k = 0; k < 2; ++k) {
                const int p = tid + k * NT;
                if (p < HH_ * NG) {
                    const int r = p >> 4;
                    const int g = p & (NG - 1);
                    for (int f = 0; f < 5; ++f) {
                        unsigned int D[6];
#pragma unroll
                        for (int u = 0; u < 6; ++u) D[u] = stg[f][r][g + u];
                        __half2 a = u2h2(0u);
#pragma unroll
                        for (int t = 0; t < K; ++t) {
                            unsigned int v;
                            if ((t & 1) == 0) v = D[t >> 1];
                            else              v = __builtin_amdgcn_alignbit(D[(t+1)>>1], D[t>>1], 16);
                            a = __hfma2(u2h2(gw.g2[t]), u2h2(v), a);
                        }
                        cwl[f][r][g] = h22u(a);
                    }
                }
            }
            __syncthreads();

            // ---------------- conv-H (per-thread, 2 cols) ---------------------
            __half2 ch[5];
#pragma unroll
            for (int f = 0; f < 5; ++f) {
                __half2 a = u2h2(0u);
#pragma unroll
                for (int t = 0; t < K; ++t)
                    a = __hfma2(u2h2(gw.g2[t]), u2h2(cwl[f][th + t][wg]), a);
                ch[f] = a;
            }

            // ring insert (static slot j)
#pragma unroll
            for (int f = 0; f < 5; ++f) hist[j][f] = ch[f];

            // ---------------- conv-D + SSIM (fires once iz >= 10) -------------
            if (c == 1 || j == K - 1) {
                __half2 a[5];
#pragma unroll
                for (int f = 0; f < 5; ++f) a[f] = u2h2(0u);
#pragma unroll
                for (int t = 0; t < K; ++t) {
                    const int s = (j + 1 + t) % K;   // compile-time after unroll
#pragma unroll
                    for (int f = 0; f < 5; ++f)
                        a[f] = __hfma2(u2h2(gw.g2[t]), hist[s][f], a[f]);
                }
                const float C1 = 1e-4f, C2 = 9e-4f;
#pragma unroll
                for (int col = 0; col < 2; ++col) {
                    const float m1  = col ? __high2float(a[0]) : __low2float(a[0]);
                    const float m2  = col ? __high2float(a[1]) : __low2float(a[1]);
                    const float e11 = col ? __high2float(a[2]) : __low2float(a[2]);
                    const float e22 = col ? __high2float(a[3]) : __low2float(a[3]);
                    const float e12 = col ? __high2float(a[4]) : __low2float(a[4]);
                    const float mu1sq = m1 * m1, mu2sq = m2 * m2, mu12 = m1 * m2;
                    const float s11 = e11 - mu1sq;
                    const float s22 = e22 - mu2sq;
                    const float s12 = e12 - mu12;
                    const float num = (2.f * mu12 + C1) * (2.f * s12 + C2);
                    const float den = (mu1sq + mu2sq + C1) * (s11 + s22 + C2);
                    ssim_acc += num * __builtin_amdgcn_rcpf(den);
                }
            }
        }
    }

    // ---------------- block reduction + one atomic ----------------------------
    float v = ssim_acc;
#pragma unroll
    for (int o = 32; o > 0; o >>= 1) v += __shfl_down(v, o);
    const int lane = tid & 63;
    const int wid  = tid >> 6;
    if (lane == 0) wsum[wid] = v;
    __syncthreads();
    if (tid == 0) {
        float s = 0.f;
#pragma unroll
        for (int i = 0; i < NT / 64; ++i) s += wsum[i];
        atomicAdd(acc, (double)s);
    }
}

__global__ void k4_final(const double* __restrict__ acc, float* __restrict__ out) {
    if (threadIdx.x == 0) {
        const double n = (double)((size_t)Dd * Hh * Ww);
        out[0] = (float)(1.0 - (*acc) / n);
    }
}

// host-side float -> half (RNE); weights are all normal-range in fp16
static unsigned short f2h(float x) {
    unsigned int u; memcpy(&u, &x, 4);
    unsigned int s = (u >> 16) & 0x8000u;
    int e = (int)((u >> 23) & 0xffu) - 112;
    unsigned int m = u & 0x7fffffu;
    if (e <= 0) return (unsigned short)s;
    unsigned int mant = m + 0xFFFu + ((m >> 13) & 1u);
    if (mant & 0x800000u) { mant = 0; e += 1; }
    return (unsigned short)(s | ((unsigned)e << 10) | (mant >> 13));
}

extern "C" void kernel_launch(void* const* d_in, const int* in_sizes, int n_in,
                              void* d_out, int out_size, void* d_ws, size_t ws_size,
                              hipStream_t stream) {
    const float* gr = (const float*)d_in[0];
    const float* gt = (const float*)d_in[1];
    float* out = (float*)d_out;

    // 1D normalized gaussian (exact outer-product factorization of the 3D window)
    GW gw;
    {
        double e[K], s = 0.0;
        for (int i = 0; i < K; ++i) {
            const double a = (double)((i - R) * (i - R));
            e[i] = exp(-a / (2.0 * 1.5 * 1.5));
            s += e[i];
        }
        for (int i = 0; i < K; ++i) {
            unsigned short h = f2h((float)(e[i] / s));
            gw.g2[i] = (unsigned int)h | ((unsigned int)h << 16);
        }
    }

    double* acc = (double*)d_ws;
    (void)hipMemsetAsync(d_ws, 0, sizeof(double), stream);

    dim3 grid(Ww / TW, Hh / TH, Dd / DC);   // 6 x 12 x 16 = 1152 blocks
    fused_ssim<<<grid, NT, 0, stream>>>(gr, gt, gw, acc);

    k4_final<<<1, 64, 0, stream>>>(acc, out);
}